// Round 1
// baseline (200.466 us; speedup 1.0000x reference)
//
#include <hip/hip_runtime.h>
#include <math.h>

#define T 32
#define K 2048
#define LOG2PI_F 1.8378770664093453f
#define LOG_K_F  7.6246189861593985f   // log(2048)
#define SP_F     0.17677669529663687f  // sqrt(1/32)
#define LOG_SP_F (-1.7328679513998633f) // log(sqrt(1/32))

// ---------------------------------------------------------------------------
// setup: zs[t,k], cterm[t,k] = -log(sp) - 0.5*log2pi - log_q[t,k], r0[k]
// ---------------------------------------------------------------------------
__global__ __launch_bounds__(256) void setup_kernel(
    const float* __restrict__ means, const float* __restrict__ log_stds,
    const float* __restrict__ eps, float* __restrict__ zs,
    float* __restrict__ cterm, float* __restrict__ r0)
{
    int tid = blockIdx.x * 256 + threadIdx.x;   // 0 .. T*K-1
    int t = tid >> 11;                          // / K
    int k = tid & (K - 1);
    float mu = means[t];
    float ls = log_stds[t];
    float std_t = expf(ls);
    float z = mu + std_t * eps[tid];
    zs[tid] = z;
    float zq = (z - mu) / std_t;
    float log_q = -0.5f * zq * zq - logf(std_t) - 0.5f * LOG2PI_F;
    cterm[tid] = -LOG_SP_F - 0.5f * LOG2PI_F - log_q;
    if (t == 0) {
        float zz = z / SP_F;
        float lp = -0.5f * zz * zz - LOG_SP_F - 0.5f * LOG2PI_F;
        r0[k] = lp - log_q;
    }
}

// ---------------------------------------------------------------------------
// one chain step: r_out[k] = cterm[i+1,k] + log((1/K) sum_j exp(r[j] - 16*(z'_k - z_j)^2))
// one wave per column k; 64 lanes x 32 j-terms in registers; r,z_i staged in LDS
// ---------------------------------------------------------------------------
__global__ __launch_bounds__(256) void step_kernel(
    const float* __restrict__ zs, const float* __restrict__ cterm,
    const float* __restrict__ r_in, float* __restrict__ r_out, int i)
{
    __shared__ float sh_r[K];
    __shared__ float sh_z[K];
    int tid = threadIdx.x;
    const float* zrow = zs + i * K;
    #pragma unroll
    for (int j = tid; j < K; j += 256) {
        sh_r[j] = r_in[j];
        sh_z[j] = zrow[j];
    }
    __syncthreads();

    int lane = tid & 63;
    int wave = tid >> 6;
    int col = blockIdx.x * 4 + wave;
    float zp = zs[(i + 1) * K + col];

    float vals[32];
    float m = -INFINITY;
    #pragma unroll
    for (int it = 0; it < 32; ++it) {
        int j = lane + (it << 6);
        float d = zp - sh_z[j];
        float v = fmaf(-16.0f * d, d, sh_r[j]);   // r[j] - 16*d*d  (0.5/sp^2 == 16 exactly)
        vals[it] = v;
        m = fmaxf(m, v);
    }
    #pragma unroll
    for (int off = 32; off >= 1; off >>= 1)
        m = fmaxf(m, __shfl_xor(m, off, 64));

    float s = 0.0f;
    #pragma unroll
    for (int it = 0; it < 32; ++it)
        s += __expf(vals[it] - m);
    #pragma unroll
    for (int off = 32; off >= 1; off >>= 1)
        s += __shfl_xor(s, off, 64);

    if (lane == 0)
        r_out[col] = cterm[(i + 1) * K + col] + m + logf(s) - LOG_K_F;
}

// ---------------------------------------------------------------------------
// final: out = m + log(sum_j exp(r[j] + L[j] - m)) - log(K),
//   L[j] = -0.5*(0.5 - zs[T-1,j])^2 - 0.5*log2pi   (like_std = 1)
// ---------------------------------------------------------------------------
__global__ __launch_bounds__(256) void final_kernel(
    const float* __restrict__ zs, const float* __restrict__ r_in,
    float* __restrict__ out)
{
    __shared__ float red[256];
    int tid = threadIdx.x;
    const float* zlast = zs + (T - 1) * K;
    float vals[8];
    float m = -INFINITY;
    #pragma unroll
    for (int it = 0; it < 8; ++it) {
        int j = tid + it * 256;
        float d = 0.5f - zlast[j];
        float v = r_in[j] + fmaf(-0.5f * d, d, -0.5f * LOG2PI_F);
        vals[it] = v;
        m = fmaxf(m, v);
    }
    red[tid] = m; __syncthreads();
    for (int off = 128; off >= 1; off >>= 1) {
        if (tid < off) red[tid] = fmaxf(red[tid], red[tid + off]);
        __syncthreads();
    }
    m = red[0]; __syncthreads();
    float s = 0.0f;
    #pragma unroll
    for (int it = 0; it < 8; ++it) s += __expf(vals[it] - m);
    red[tid] = s; __syncthreads();
    for (int off = 128; off >= 1; off >>= 1) {
        if (tid < off) red[tid] += red[tid + off];
        __syncthreads();
    }
    if (tid == 0) out[0] = m + logf(red[0]) - LOG_K_F;
}

extern "C" void kernel_launch(void* const* d_in, const int* in_sizes, int n_in,
                              void* d_out, int out_size, void* d_ws, size_t ws_size,
                              hipStream_t stream) {
    const float* means    = (const float*)d_in[0];
    const float* log_stds = (const float*)d_in[1];
    const float* eps      = (const float*)d_in[2];
    float* out = (float*)d_out;

    float* ws    = (float*)d_ws;
    float* zs    = ws;               // T*K
    float* cterm = ws + T * K;       // T*K
    float* rb0   = ws + 2 * T * K;   // K
    float* rb1   = rb0 + K;          // K

    setup_kernel<<<(T * K) / 256, 256, 0, stream>>>(means, log_stds, eps, zs, cterm, rb0);

    float* rin = rb0;
    float* rout = rb1;
    for (int i = 0; i < T - 1; ++i) {
        step_kernel<<<K / 4, 256, 0, stream>>>(zs, cterm, rin, rout, i);
        float* tmp = rin; rin = rout; rout = tmp;
    }

    final_kernel<<<1, 256, 0, stream>>>(zs, rin, out);
}